// Round 7
// baseline (1028.785 us; speedup 1.0000x reference)
//
#include <hip/hip_runtime.h>
#include <hip/hip_bf16.h>
#include <stdint.h>

// ---------------------------------------------------------------------------
// Transformer block, B=4 S=2048 E=2048 H=1.
// H=1 -> softmax over size-1 axis == 1.0 -> attn_out = x @ w_kv + b_kv.
// Pipeline: t1 = x + (x@w_kv + b_kv); h = LN1(t1);
//           g = gelu(h@w_fc + b_fc);  t2 = x + (g@w_mproj + b_mproj);
//           out = LN2(t2).
// GEMM: 256x256 tile, 8 waves (2Mx4N), BK=64, 128KB LDS dbuf.
// R7: intra-wave software pipeline. R3/R5/R6 all measured ~6000 cyc/K-tile
// = serial sum of LDS reads (~2300) + MFMA (~2480) + stage/barriers: the
// per-phase {reads -> barrier -> lgkmcnt(0) -> MFMA -> barrier} lockstep
// leaves the LDS pipe empty during MFMA and vice versa. Now: 4 clusters per
// tile; cluster c's operands are read during cluster c-1 under counted
// lgkmcnt; C4 pre-reads next tile's A0/B0 under q11's MFMAs and across the
// tile-end barrier. Stages (t+1 -> other buf) issue in C1/C2, retired by
// vmcnt(0) (issued ~2 clusters earlier) + mid-tile barrier before C4's
// cross-buffer pre-reads. 2 barriers/tile (was 8).
// ---------------------------------------------------------------------------

typedef __attribute__((ext_vector_type(4))) float f32x4;
typedef __attribute__((ext_vector_type(8))) __bf16 bf16x8;
typedef __attribute__((ext_vector_type(8))) unsigned short ushort8;

__device__ __forceinline__ unsigned short f2bf(float f) {
  unsigned int u = __float_as_uint(f);
  return (unsigned short)((u + 0x7FFFu + ((u >> 16) & 1u)) >> 16);  // RNE
}

__device__ __forceinline__ void gload_lds16(const void* g, void* l) {
  __builtin_amdgcn_global_load_lds(
      (const __attribute__((address_space(1))) unsigned int*)(uintptr_t)g,
      (__attribute__((address_space(3))) unsigned int*)(unsigned int)(uintptr_t)l,
      16, 0, 0);
}

#define WAITLGK(n) asm volatile("s_waitcnt lgkmcnt(" #n ")" ::: "memory")
#define WAITVM(n) asm volatile("s_waitcnt vmcnt(" #n ")" ::: "memory")
#define SBAR() __builtin_amdgcn_s_barrier()
#define SCHED0() __builtin_amdgcn_sched_barrier(0)

// ---------------------------------------------------------------------------
// f32 -> bf16 convert
// ---------------------------------------------------------------------------
__global__ __launch_bounds__(256) void cvt_bf16_kernel(
    const float* __restrict__ in, unsigned short* __restrict__ out, int n8) {
  int i = blockIdx.x * 256 + threadIdx.x;
  if (i >= n8) return;
  const size_t base = (size_t)i * 8;
  float4 a = *(const float4*)(in + base);
  float4 b = *(const float4*)(in + base + 4);
  ushort8 o;
  o[0] = f2bf(a.x); o[1] = f2bf(a.y); o[2] = f2bf(a.z); o[3] = f2bf(a.w);
  o[4] = f2bf(b.x); o[5] = f2bf(b.y); o[6] = f2bf(b.z); o[7] = f2bf(b.w);
  *(ushort8*)(out + base) = o;
}

// ---------------------------------------------------------------------------
// Transpose + convert: W (R x C f32) -> WT (C x R bf16)
// ---------------------------------------------------------------------------
__global__ __launch_bounds__(256) void transpose_cvt(
    const float* __restrict__ W, unsigned short* __restrict__ WT, int R, int C) {
  __shared__ unsigned short t[64][66];
  const int c0 = blockIdx.x * 64, r0 = blockIdx.y * 64;
  const int tid = threadIdx.x;
  const int lr = tid >> 4;
  const int lc = (tid & 15) * 4;
#pragma unroll
  for (int p = 0; p < 4; ++p) {
    const int r = lr + p * 16;
    float4 v = *(const float4*)(W + (size_t)(r0 + r) * C + c0 + lc);
    t[r][lc + 0] = f2bf(v.x);
    t[r][lc + 1] = f2bf(v.y);
    t[r][lc + 2] = f2bf(v.z);
    t[r][lc + 3] = f2bf(v.w);
  }
  __syncthreads();
#pragma unroll
  for (int p = 0; p < 4; ++p) {
    const int oc = lr + p * 16;
    ushort4 o;
    o.x = t[lc + 0][oc];
    o.y = t[lc + 1][oc];
    o.z = t[lc + 2][oc];
    o.w = t[lc + 3][oc];
    *(ushort4*)(WT + (size_t)(c0 + oc) * R + r0 + lc) = o;
  }
}

// ---------------------------------------------------------------------------
// 256x256 pipelined bf16 GEMM (intra-wave cluster pipeline).
// A: MxK, BT: NxK (bf16, rows%256==0, K%128==0).
// EPI 0: f32 out = acc+bias+xres; EPI 1: bf16 gelu(acc+bias).
// ---------------------------------------------------------------------------
template <int EPI>
__global__ __launch_bounds__(512, 2) void gemm256(
    const unsigned short* __restrict__ A, const unsigned short* __restrict__ BT,
    const float* __restrict__ bias, const float* __restrict__ xres,
    void* __restrict__ out, int N, int K) {
  // L[buf][op][region][128*64] ; each region 16 KiB; total 128 KiB.
  __shared__ unsigned short L[2][2][2][8192];

  const int tid = threadIdx.x;
  const int lane = tid & 63;
  const int w = tid >> 6;  // 0..7
  const int wm = w >> 2;   // 0..1 -> rows wm*128
  const int wn = w & 3;    // 0..3 -> cols wn*64
  const int l15 = lane & 15;

  const int nbn = N / 256;
  const int nwg = gridDim.x;
  const int bid = blockIdx.x;
  const int wg = (bid & 7) * (nwg >> 3) + (bid >> 3);  // XCD-bijective (nwg%8==0)
  const int bm = wg / nbn, bn = wg % nbn;

  const int nt = K / 64;  // even

  // ---- staging lane addressing (identical to R6, which passed) ----
  const int srow = w * 8 + (lane >> 3);
  const int schunk = (lane & 7) ^ ((lane >> 3) & 7);
  const unsigned short* pb[2][2][2];  // [op][h][j]
#pragma unroll
  for (int h = 0; h < 2; ++h)
#pragma unroll
    for (int j = 0; j < 2; ++j) {
      pb[0][h][j] =
          A + (size_t)(bm * 256 + j * 128 + h * 64 + srow) * K + schunk * 8;
      pb[1][h][j] = BT +
                    (size_t)(bn * 256 + ((srow >> 5) + 2 * j) * 64 + h * 32 +
                             (srow & 31)) * K +
                    schunk * 8;
    }

#define STAGE(BUF, OP, H, TILE)                                            \
  {                                                                        \
    const size_t ko_ = (size_t)(TILE) * 64;                                \
    gload_lds16(pb[OP][H][0] + ko_, &L[BUF][OP][H][w * 512]);              \
    gload_lds16(pb[OP][H][1] + ko_, &L[BUF][OP][H][w * 512 + 4096]);       \
  }

  // ---- fragment read addressing (identical to R6) ----
  const int kq = lane >> 4;
  const int x7 = lane & 7;
  const int cc0 = ((kq ^ x7) << 4);
  const int cc1 = (((4 + kq) ^ x7) << 4);
  const int rAoff = (wm * 64 + l15) * 128;
  const int rBoff = (wn * 32 + l15) * 128;

  f32x4 acc[8][4] = {};
  bf16x8 a0F[4][2], a1F[4][2], b0F[2][2], b1F[2][2];

#define RD_A(BUF, H, DST)                                              \
  {                                                                    \
    const char* p_ = (const char*)&L[BUF][0][H][0] + rAoff;            \
    _Pragma("unroll") for (int mf = 0; mf < 4; ++mf) {                 \
      DST[mf][0] = *(const bf16x8*)(p_ + mf * 2048 + cc0);             \
      DST[mf][1] = *(const bf16x8*)(p_ + mf * 2048 + cc1);             \
    }                                                                  \
  }
#define RD_B(BUF, H, DST)                                              \
  {                                                                    \
    const char* p_ = (const char*)&L[BUF][1][H][0] + rBoff;            \
    _Pragma("unroll") for (int nf = 0; nf < 2; ++nf) {                 \
      DST[nf][0] = *(const bf16x8*)(p_ + nf * 2048 + cc0);             \
      DST[nf][1] = *(const bf16x8*)(p_ + nf * 2048 + cc1);             \
    }                                                                  \
  }
#define CLUSTER(ASET, BSET, MO, NO)                                         \
  __builtin_amdgcn_s_setprio(1);                                            \
  _Pragma("unroll") for (int mf = 0; mf < 4; ++mf)                          \
      _Pragma("unroll") for (int nf = 0; nf < 2; ++nf)                      \
          _Pragma("unroll") for (int ks = 0; ks < 2; ++ks)                  \
              acc[MO + mf][NO + nf] =                                       \
                  __builtin_amdgcn_mfma_f32_16x16x32_bf16(                  \
                      ASET[mf][ks], BSET[nf][ks], acc[MO + mf][NO + nf],    \
                      0, 0, 0);                                             \
  __builtin_amdgcn_s_setprio(0);

  // One K-tile: reads from buf RB, stages tile TS into buf SB.
  // C1: issue B1-reads + A-stages; wait(4) releases pre-read A0,B0; q00.
  // C2: issue A1-reads + B-stages; wait(8) releases B1; q01.
  // C3: wait(0) releases A1; q10; vmcnt(0) (stages landed); barrier.
  // C4: pre-read next tile's A0,B0 from SB; q11 (reg-resident); barrier.
#define TILE_BODY(RB, SB, TS)                                               \
  RD_B(RB, 1, b1F);                                                         \
  STAGE(SB, 0, 0, TS); STAGE(SB, 0, 1, TS);                                 \
  WAITLGK(4); SCHED0();                                                     \
  CLUSTER(a0F, b0F, 0, 0);                                                  \
  RD_A(RB, 1, a1F);                                                         \
  STAGE(SB, 1, 0, TS); STAGE(SB, 1, 1, TS);                                 \
  WAITLGK(8); SCHED0();                                                     \
  CLUSTER(a0F, b1F, 0, 2);                                                  \
  WAITLGK(0); SCHED0();                                                     \
  CLUSTER(a1F, b0F, 4, 0);                                                  \
  WAITVM(0);                                                                \
  SBAR();                                                                   \
  RD_A(SB, 0, a0F);                                                         \
  RD_B(SB, 0, b0F);                                                         \
  SCHED0();                                                                 \
  CLUSTER(a1F, b1F, 4, 2);                                                  \
  SBAR();

  // ---- prologue: stage tile 0 into buf0, pre-read its A0,B0 ----
  STAGE(0, 0, 0, 0); STAGE(0, 0, 1, 0); STAGE(0, 1, 0, 0); STAGE(0, 1, 1, 0);
  WAITVM(0);
  SBAR();
  RD_A(0, 0, a0F);
  RD_B(0, 0, b0F);

  for (int t2 = 0; t2 < nt; t2 += 2) {
    const int tp1 = (t2 + 1 < nt) ? t2 + 1 : nt - 1;  // clamped (idempotent)
    const int tp2 = (t2 + 2 < nt) ? t2 + 2 : nt - 1;
    TILE_BODY(0, 1, tp1);  // tile t2   : read buf0, stage t2+1 -> buf1
    TILE_BODY(1, 0, tp2);  // tile t2+1 : read buf1, stage t2+2 -> buf0
  }
  WAITLGK(0);  // drain dangling pre-reads
  WAITVM(0);

  // ---- epilogue: C/D layout col = lane&15, row = (lane>>4)*4 + reg ----
  const int col0 = bn * 256 + wn * 64 + l15;
  const int row0 = bm * 256 + wm * 128 + ((lane >> 4) << 2);
  float bv[4];
#pragma unroll
  for (int n = 0; n < 4; ++n) bv[n] = bias[col0 + n * 16];
#pragma unroll
  for (int mf = 0; mf < 8; ++mf) {
#pragma unroll
    for (int j = 0; j < 4; ++j) {
      const size_t row = (size_t)(row0 + mf * 16 + j);
#pragma unroll
      for (int n = 0; n < 4; ++n) {
        const size_t idx = row * N + col0 + n * 16;
        float v = acc[mf][n][j] + bv[n];
        if (EPI == 0) {
          ((float*)out)[idx] = v + xres[idx];
        } else {
          float ge = 0.5f * v * (1.0f + erff(v * 0.7071067811865475f));
          ((unsigned short*)out)[idx] = f2bf(ge);
        }
      }
    }
  }
#undef RD_A
#undef RD_B
#undef CLUSTER
#undef STAGE
#undef TILE_BODY
}

// ---------------------------------------------------------------------------
// Row LayerNorm over E=2048: one block per row, 8 elems/thread.
// ---------------------------------------------------------------------------
template <int OUT_BF16>
__global__ __launch_bounds__(256) void ln_row(const float* __restrict__ tin,
                                              const float* __restrict__ gw,
                                              const float* __restrict__ bw,
                                              void* __restrict__ outp) {
  const int row = blockIdx.x;
  const int tid = threadIdx.x;
  const size_t base = (size_t)row * 2048 + tid * 8;
  alignas(16) float v[8];
  *(float4*)(v) = *(const float4*)(tin + base);
  *(float4*)(v + 4) = *(const float4*)(tin + base + 4);
  float s = 0.f, q = 0.f;
#pragma unroll
  for (int i = 0; i < 8; ++i) { s += v[i]; q += v[i] * v[i]; }
#pragma unroll
  for (int m = 32; m >= 1; m >>= 1) {
    s += __shfl_xor(s, m);
    q += __shfl_xor(q, m);
  }
  __shared__ float red[8];
  if ((tid & 63) == 0) {
    red[tid >> 6] = s;
    red[4 + (tid >> 6)] = q;
  }
  __syncthreads();
  s = red[0] + red[1] + red[2] + red[3];
  q = red[4] + red[5] + red[6] + red[7];
  const float mean = s * (1.0f / 2048.0f);
  float var = q * (1.0f / 2048.0f) - mean * mean;
  var = fmaxf(var, 0.0f);
  const float rstd = rsqrtf(var + 1e-5f);
  alignas(16) float gv[8], bv[8];
  *(float4*)(gv) = *(const float4*)(gw + (size_t)tid * 8);
  *(float4*)(gv + 4) = *(const float4*)(gw + (size_t)tid * 8 + 4);
  *(float4*)(bv) = *(const float4*)(bw + (size_t)tid * 8);
  *(float4*)(bv + 4) = *(const float4*)(bw + (size_t)tid * 8 + 4);
  if (OUT_BF16) {
    ushort8 o;
#pragma unroll
    for (int i = 0; i < 8; ++i)
      o[i] = f2bf((v[i] - mean) * rstd * gv[i] + bv[i]);
    *(ushort8*)((unsigned short*)outp + base) = o;
  } else {
    alignas(16) float r[8];
#pragma unroll
    for (int i = 0; i < 8; ++i) r[i] = (v[i] - mean) * rstd * gv[i] + bv[i];
    *(float4*)((float*)outp + base) = *(float4*)(r);
    *(float4*)((float*)outp + base + 4) = *(float4*)(r + 4);
  }
}

// ---------------------------------------------------------------------------
// Launcher — workspace-size-adaptive (R2+ evidence: full path taken).
// ---------------------------------------------------------------------------
extern "C" void kernel_launch(void* const* d_in, const int* in_sizes, int n_in,
                              void* d_out, int out_size, void* d_ws,
                              size_t ws_size, hipStream_t stream) {
  constexpr int M = 8192;  // B*S
  constexpr int E = 2048;
  constexpr int F = 8192;  // 4*E
  const size_t MiB = 1ull << 20;

  const float* x = (const float*)d_in[0];
  // d_in[1] mask, d_in[2] w_attn, d_in[3] b_attn: dead (softmax over size-1)
  const float* w_kv = (const float*)d_in[4];
  const float* b_kv = (const float*)d_in[5];
  const float* ln1_g = (const float*)d_in[6];
  const float* ln1_b = (const float*)d_in[7];
  const float* w_fc = (const float*)d_in[8];
  const float* b_fc = (const float*)d_in[9];
  const float* w_mproj = (const float*)d_in[10];
  const float* b_mproj = (const float*)d_in[11];
  const float* ln2_g = (const float*)d_in[12];
  const float* ln2_b = (const float*)d_in[13];
  float* out = (float*)d_out;
  char* ws = (char*)d_ws;

  float* tbuf = out;  // t1/t2 live in d_out; in-place LN is safe

  int nch;
  unsigned short *xb, *wkvT, *wfcT, *wmpT, *hb, *gch;
  if (ws_size >= 224 * MiB) {
    nch = 1;
    gch = (unsigned short*)(ws + 0);  // 128Mi; aliases xb+wkvT (dead by then)
    xb = (unsigned short*)(ws + 0);
    wkvT = (unsigned short*)(ws + 32 * MiB);
    wfcT = (unsigned short*)(ws + 128 * MiB);
    wmpT = (unsigned short*)(ws + 160 * MiB);
    hb = (unsigned short*)(ws + 192 * MiB);
  } else if (ws_size >= 160 * MiB) {
    nch = 2;
    gch = (unsigned short*)(ws + 0);
    xb = (unsigned short*)(ws + 0);
    wkvT = (unsigned short*)(ws + 32 * MiB);
    hb = (unsigned short*)(ws + 64 * MiB);
    wfcT = (unsigned short*)(ws + 96 * MiB);
    wmpT = (unsigned short*)(ws + 128 * MiB);
  } else {
    nch = 4;
    gch = (unsigned short*)(ws + 0);
    xb = (unsigned short*)(ws + 0);
    wkvT = (unsigned short*)(ws + 32 * MiB);
    hb = (unsigned short*)(ws + 32 * MiB);
    wfcT = (unsigned short*)(ws + 64 * MiB);
    wmpT = (unsigned short*)(ws + 96 * MiB);
  }

  cvt_bf16_kernel<<<(M * E / 8 + 255) / 256, 256, 0, stream>>>(x, xb, M * E / 8);
  transpose_cvt<<<dim3(E / 64, E / 64), 256, 0, stream>>>(w_kv, wkvT, E, E);
  transpose_cvt<<<dim3(F / 64, E / 64), 256, 0, stream>>>(w_fc, wfcT, E, F);
  transpose_cvt<<<dim3(E / 64, F / 64), 256, 0, stream>>>(w_mproj, wmpT, F, E);

  // t1 = x @ w_kv + b_kv + x
  gemm256<0><<<(M / 256) * (E / 256), 512, 0, stream>>>(xb, wkvT, b_kv, x,
                                                        tbuf, E, E);
  // h = LN1(t1) -> bf16
  ln_row<1><<<M, 256, 0, stream>>>(tbuf, ln1_g, ln1_b, hb);
  // g = gelu(h @ w_fc + b_fc); t2 = x + g @ w_mproj + b_mproj  (M-chunked)
  const int Mc = M / nch;
  for (int c = 0; c < nch; ++c) {
    const size_t roff = (size_t)c * Mc;
    gemm256<1><<<(Mc / 256) * (F / 256), 512, 0, stream>>>(
        hb + roff * E, wfcT, b_fc, nullptr, gch, F, E);
    gemm256<0><<<(Mc / 256) * (E / 256), 512, 0, stream>>>(
        gch, wmpT, b_mproj, x + roff * E, tbuf + roff * E, E, F);
  }
  // out = LN2(t2) in place
  ln_row<0><<<M, 256, 0, stream>>>(tbuf, ln2_g, ln2_b, out);
}

// Round 8
// 693.412 us; speedup vs baseline: 1.4837x; 1.4837x over previous
//
#include <hip/hip_runtime.h>
#include <hip/hip_bf16.h>
#include <stdint.h>

// ---------------------------------------------------------------------------
// Transformer block, B=4 S=2048 E=2048 H=1.
// H=1 -> softmax over size-1 axis == 1.0 -> attn_out = x @ w_kv + b_kv.
// Pipeline: t1 = x + (x@w_kv + b_kv); h = LN1(t1);
//           g = gelu(h@w_fc + b_fc);  t2 = x + (g@w_mproj + b_mproj);
//           out = LN2(t2).
// GEMM: 256x256 tile, 8 waves (2Mx4N), BK=64, 128KB LDS dbuf, m201-faithful
// 8-phase stream: per phase exactly {8 or 4 ds_read_b128} + {1 half-tile
// stage (2 global_load_lds)} + barrier + lgkmcnt(0) + sched_barrier(0) +
// 16 MFMA; ONE counted vmcnt(6) per K-tile at ph4 (never 0 in loop).
// Reads: ph1 A0(t), ph2 B1(t), ph3 A1(t), ph4 B0(t+1) cross-buffer.
// Stages (all -> buf(t)=buf(t+2)): ph1 B0(t+2), ph2 A0(t+2), ph3 B1(t+2),
// ph4 A1(t+2) — each region overwritten exactly one barrier after its last
// LDS read. vmcnt(6)@ph4 retires tile t+1 fully + B0(t+2) (= the next 4
// phases' reads); every stage has >=3 phases (~2400cyc) of HBM cover.
// (R7 regressed from VGPR spills: reverted the register double-pipeline.)
// ---------------------------------------------------------------------------

typedef __attribute__((ext_vector_type(4))) float f32x4;
typedef __attribute__((ext_vector_type(8))) __bf16 bf16x8;
typedef __attribute__((ext_vector_type(8))) unsigned short ushort8;

__device__ __forceinline__ unsigned short f2bf(float f) {
  unsigned int u = __float_as_uint(f);
  return (unsigned short)((u + 0x7FFFu + ((u >> 16) & 1u)) >> 16);  // RNE
}

__device__ __forceinline__ void gload_lds16(const void* g, void* l) {
  __builtin_amdgcn_global_load_lds(
      (const __attribute__((address_space(1))) unsigned int*)(uintptr_t)g,
      (__attribute__((address_space(3))) unsigned int*)(unsigned int)(uintptr_t)l,
      16, 0, 0);
}

#define WAITLGK(n) asm volatile("s_waitcnt lgkmcnt(" #n ")" ::: "memory")
#define WAITVM(n) asm volatile("s_waitcnt vmcnt(" #n ")" ::: "memory")
#define SBAR() __builtin_amdgcn_s_barrier()
#define SCHED0() __builtin_amdgcn_sched_barrier(0)

// ---------------------------------------------------------------------------
// f32 -> bf16 convert
// ---------------------------------------------------------------------------
__global__ __launch_bounds__(256) void cvt_bf16_kernel(
    const float* __restrict__ in, unsigned short* __restrict__ out, int n8) {
  int i = blockIdx.x * 256 + threadIdx.x;
  if (i >= n8) return;
  const size_t base = (size_t)i * 8;
  float4 a = *(const float4*)(in + base);
  float4 b = *(const float4*)(in + base + 4);
  ushort8 o;
  o[0] = f2bf(a.x); o[1] = f2bf(a.y); o[2] = f2bf(a.z); o[3] = f2bf(a.w);
  o[4] = f2bf(b.x); o[5] = f2bf(b.y); o[6] = f2bf(b.z); o[7] = f2bf(b.w);
  *(ushort8*)(out + base) = o;
}

// ---------------------------------------------------------------------------
// Transpose + convert: W (R x C f32) -> WT (C x R bf16)
// ---------------------------------------------------------------------------
__global__ __launch_bounds__(256) void transpose_cvt(
    const float* __restrict__ W, unsigned short* __restrict__ WT, int R, int C) {
  __shared__ unsigned short t[64][66];
  const int c0 = blockIdx.x * 64, r0 = blockIdx.y * 64;
  const int tid = threadIdx.x;
  const int lr = tid >> 4;
  const int lc = (tid & 15) * 4;
#pragma unroll
  for (int p = 0; p < 4; ++p) {
    const int r = lr + p * 16;
    float4 v = *(const float4*)(W + (size_t)(r0 + r) * C + c0 + lc);
    t[r][lc + 0] = f2bf(v.x);
    t[r][lc + 1] = f2bf(v.y);
    t[r][lc + 2] = f2bf(v.z);
    t[r][lc + 3] = f2bf(v.w);
  }
  __syncthreads();
#pragma unroll
  for (int p = 0; p < 4; ++p) {
    const int oc = lr + p * 16;
    ushort4 o;
    o.x = t[lc + 0][oc];
    o.y = t[lc + 1][oc];
    o.z = t[lc + 2][oc];
    o.w = t[lc + 3][oc];
    *(ushort4*)(WT + (size_t)(c0 + oc) * R + r0 + lc) = o;
  }
}

// ---------------------------------------------------------------------------
// 256x256 8-phase bf16 GEMM (m201 stream). A: MxK, BT: NxK (bf16,
// rows%256==0, K%128==0). EPI 0: f32 = acc+bias+xres; EPI 1: bf16 gelu.
// ---------------------------------------------------------------------------
template <int EPI>
__global__ __launch_bounds__(512, 2) void gemm256(
    const unsigned short* __restrict__ A, const unsigned short* __restrict__ BT,
    const float* __restrict__ bias, const float* __restrict__ xres,
    void* __restrict__ out, int N, int K) {
  // L[buf][op][region][128*64] ; each region 16 KiB; total 128 KiB.
  __shared__ unsigned short L[2][2][2][8192];

  const int tid = threadIdx.x;
  const int lane = tid & 63;
  const int w = tid >> 6;  // 0..7
  const int wm = w >> 2;   // 0..1 -> rows wm*128
  const int wn = w & 3;    // 0..3 -> cols wn*64
  const int l15 = lane & 15;

  const int nbn = N / 256;
  const int nwg = gridDim.x;
  const int bid = blockIdx.x;
  const int wg = (bid & 7) * (nwg >> 3) + (bid >> 3);  // XCD-bijective (nwg%8==0)
  const int bm = wg / nbn, bn = wg % nbn;

  const int nt = K / 64;  // >= 2

  // ---- staging lane addressing (identical to R6, which passed) ----
  const int srow = w * 8 + (lane >> 3);
  const int schunk = (lane & 7) ^ ((lane >> 3) & 7);
  const unsigned short* pb[2][2][2];  // [op][h][j]
#pragma unroll
  for (int h = 0; h < 2; ++h)
#pragma unroll
    for (int j = 0; j < 2; ++j) {
      pb[0][h][j] =
          A + (size_t)(bm * 256 + j * 128 + h * 64 + srow) * K + schunk * 8;
      pb[1][h][j] = BT +
                    (size_t)(bn * 256 + ((srow >> 5) + 2 * j) * 64 + h * 32 +
                             (srow & 31)) * K +
                    schunk * 8;
    }

#define STAGE(BUF, OP, H, TILE)                                            \
  {                                                                        \
    const size_t ko_ = (size_t)(TILE) * 64;                                \
    gload_lds16(pb[OP][H][0] + ko_, &L[BUF][OP][H][w * 512]);              \
    gload_lds16(pb[OP][H][1] + ko_, &L[BUF][OP][H][w * 512 + 4096]);       \
  }

  // ---- fragment read addressing (identical to R6) ----
  const int kq = lane >> 4;
  const int x7 = lane & 7;
  const int cc0 = ((kq ^ x7) << 4);
  const int cc1 = (((4 + kq) ^ x7) << 4);
  const int rAoff = (wm * 64 + l15) * 128;
  const int rBoff = (wn * 32 + l15) * 128;

  f32x4 acc[8][4] = {};
  bf16x8 aF[4][2], b0F[2][2], b1F[2][2];

#define RD_A(BUF, H)                                                   \
  {                                                                    \
    const char* p_ = (const char*)&L[BUF][0][H][0] + rAoff;            \
    _Pragma("unroll") for (int mf = 0; mf < 4; ++mf) {                 \
      aF[mf][0] = *(const bf16x8*)(p_ + mf * 2048 + cc0);              \
      aF[mf][1] = *(const bf16x8*)(p_ + mf * 2048 + cc1);              \
    }                                                                  \
  }
#define RD_B(BUF, H, DST)                                              \
  {                                                                    \
    const char* p_ = (const char*)&L[BUF][1][H][0] + rBoff;            \
    _Pragma("unroll") for (int nf = 0; nf < 2; ++nf) {                 \
      DST[nf][0] = *(const bf16x8*)(p_ + nf * 2048 + cc0);             \
      DST[nf][1] = *(const bf16x8*)(p_ + nf * 2048 + cc1);             \
    }                                                                  \
  }
#define CLUSTER(BSET, MO, NO)                                               \
  __builtin_amdgcn_s_setprio(1);                                            \
  _Pragma("unroll") for (int mf = 0; mf < 4; ++mf)                          \
      _Pragma("unroll") for (int nf = 0; nf < 2; ++nf)                      \
          _Pragma("unroll") for (int ks = 0; ks < 2; ++ks)                  \
              acc[MO + mf][NO + nf] =                                       \
                  __builtin_amdgcn_mfma_f32_16x16x32_bf16(                  \
                      aF[mf][ks], BSET[nf][ks], acc[MO + mf][NO + nf],      \
                      0, 0, 0);                                             \
  __builtin_amdgcn_s_setprio(0);

  // ---- prologue: stage tiles 0,1 in steady FIFO order {B0,A0,B1,A1};
  //      vmcnt(6) retires all(0)+B0(1); pre-read B0(0) into regs. ----
  STAGE(0, 1, 0, 0); STAGE(0, 0, 0, 0); STAGE(0, 1, 1, 0); STAGE(0, 0, 1, 0);
  STAGE(1, 1, 0, 1); STAGE(1, 0, 0, 1); STAGE(1, 1, 1, 1); STAGE(1, 0, 1, 1);
  WAITVM(6);
  SBAR();
  RD_B(0, 0, b0F);
  WAITLGK(0);  // retire pre-read before any ph1 stage overwrites B0 regions
  SBAR();

  for (int t = 0; t < nt; ++t) {
    const int cb = t & 1, ob = cb ^ 1;
    const int ts = (t + 2 < nt) ? t + 2 : nt - 1;  // clamp: idempotent/dead
    // ---- ph1: q00; reads A0(t) [8]; stage B0(t+2) ----
    RD_A(cb, 0);
    STAGE(cb, 1, 0, ts);
    SBAR();
    WAITLGK(0); SCHED0();
    CLUSTER(b0F, 0, 0);
    SBAR();
    // ---- ph2: q01; reads B1(t) [4]; stage A0(t+2) ----
    RD_B(cb, 1, b1F);
    STAGE(cb, 0, 0, ts);
    SBAR();
    WAITLGK(0); SCHED0();
    CLUSTER(b1F, 0, 2);
    SBAR();
    // ---- ph3: q10; reads A1(t) [8]; stage B1(t+2) ----
    RD_A(cb, 1);
    STAGE(cb, 1, 1, ts);
    SBAR();
    WAITLGK(0); SCHED0();
    CLUSTER(b0F, 4, 0);
    SBAR();
    // ---- ph4: q11; reads B0(t+1) [4, cross-buffer]; stage A1(t+2);
    //      vmcnt(6): retires tile t+1 fully + B0(t+2) ----
    RD_B(ob, 0, b0F);
    STAGE(cb, 0, 1, ts);
    SBAR();
    WAITLGK(0); SCHED0();
    CLUSTER(b1F, 4, 2);
    WAITVM(6);
    SBAR();
  }
  WAITVM(0);  // drain straggler stages

  // ---- epilogue: C/D layout col = lane&15, row = (lane>>4)*4 + reg ----
  const int col0 = bn * 256 + wn * 64 + l15;
  const int row0 = bm * 256 + wm * 128 + ((lane >> 4) << 2);
  float bv[4];
#pragma unroll
  for (int n = 0; n < 4; ++n) bv[n] = bias[col0 + n * 16];
#pragma unroll
  for (int mf = 0; mf < 8; ++mf) {
#pragma unroll
    for (int j = 0; j < 4; ++j) {
      const size_t row = (size_t)(row0 + mf * 16 + j);
#pragma unroll
      for (int n = 0; n < 4; ++n) {
        const size_t idx = row * N + col0 + n * 16;
        float v = acc[mf][n][j] + bv[n];
        if (EPI == 0) {
          ((float*)out)[idx] = v + xres[idx];
        } else {
          float ge = 0.5f * v * (1.0f + erff(v * 0.7071067811865475f));
          ((unsigned short*)out)[idx] = f2bf(ge);
        }
      }
    }
  }
#undef RD_A
#undef RD_B
#undef CLUSTER
#undef STAGE
}

// ---------------------------------------------------------------------------
// Row LayerNorm over E=2048: one block per row, 8 elems/thread.
// ---------------------------------------------------------------------------
template <int OUT_BF16>
__global__ __launch_bounds__(256) void ln_row(const float* __restrict__ tin,
                                              const float* __restrict__ gw,
                                              const float* __restrict__ bw,
                                              void* __restrict__ outp) {
  const int row = blockIdx.x;
  const int tid = threadIdx.x;
  const size_t base = (size_t)row * 2048 + tid * 8;
  alignas(16) float v[8];
  *(float4*)(v) = *(const float4*)(tin + base);
  *(float4*)(v + 4) = *(const float4*)(tin + base + 4);
  float s = 0.f, q = 0.f;
#pragma unroll
  for (int i = 0; i < 8; ++i) { s += v[i]; q += v[i] * v[i]; }
#pragma unroll
  for (int m = 32; m >= 1; m >>= 1) {
    s += __shfl_xor(s, m);
    q += __shfl_xor(q, m);
  }
  __shared__ float red[8];
  if ((tid & 63) == 0) {
    red[tid >> 6] = s;
    red[4 + (tid >> 6)] = q;
  }
  __syncthreads();
  s = red[0] + red[1] + red[2] + red[3];
  q = red[4] + red[5] + red[6] + red[7];
  const float mean = s * (1.0f / 2048.0f);
  float var = q * (1.0f / 2048.0f) - mean * mean;
  var = fmaxf(var, 0.0f);
  const float rstd = rsqrtf(var + 1e-5f);
  alignas(16) float gv[8], bv[8];
  *(float4*)(gv) = *(const float4*)(gw + (size_t)tid * 8);
  *(float4*)(gv + 4) = *(const float4*)(gw + (size_t)tid * 8 + 4);
  *(float4*)(bv) = *(const float4*)(bw + (size_t)tid * 8);
  *(float4*)(bv + 4) = *(const float4*)(bw + (size_t)tid * 8 + 4);
  if (OUT_BF16) {
    ushort8 o;
#pragma unroll
    for (int i = 0; i < 8; ++i)
      o[i] = f2bf((v[i] - mean) * rstd * gv[i] + bv[i]);
    *(ushort8*)((unsigned short*)outp + base) = o;
  } else {
    alignas(16) float r[8];
#pragma unroll
    for (int i = 0; i < 8; ++i) r[i] = (v[i] - mean) * rstd * gv[i] + bv[i];
    *(float4*)((float*)outp + base) = *(float4*)(r);
    *(float4*)((float*)outp + base + 4) = *(float4*)(r + 4);
  }
}

// ---------------------------------------------------------------------------
// Launcher — workspace-size-adaptive (R2+ evidence: full path taken).
// ---------------------------------------------------------------------------
extern "C" void kernel_launch(void* const* d_in, const int* in_sizes, int n_in,
                              void* d_out, int out_size, void* d_ws,
                              size_t ws_size, hipStream_t stream) {
  constexpr int M = 8192;  // B*S
  constexpr int E = 2048;
  constexpr int F = 8192;  // 4*E
  const size_t MiB = 1ull << 20;

  const float* x = (const float*)d_in[0];
  // d_in[1] mask, d_in[2] w_attn, d_in[3] b_attn: dead (softmax over size-1)
  const float* w_kv = (const float*)d_in[4];
  const float* b_kv = (const float*)d_in[5];
  const float* ln1_g = (const float*)d_in[6];
  const float* ln1_b = (const float*)d_in[7];
  const float* w_fc = (const float*)d_in[8];
  const float* b_fc = (const float*)d_in[9];
  const float* w_mproj = (const float*)d_in[10];
  const float* b_mproj = (const float*)d_in[11];
  const float* ln2_g = (const float*)d_in[12];
  const float* ln2_b = (const float*)d_in[13];
  float* out = (float*)d_out;
  char* ws = (char*)d_ws;

  float* tbuf = out;  // t1/t2 live in d_out; in-place LN is safe

  int nch;
  unsigned short *xb, *wkvT, *wfcT, *wmpT, *hb, *gch;
  if (ws_size >= 224 * MiB) {
    nch = 1;
    gch = (unsigned short*)(ws + 0);  // 128Mi; aliases xb+wkvT (dead by then)
    xb = (unsigned short*)(ws + 0);
    wkvT = (unsigned short*)(ws + 32 * MiB);
    wfcT = (unsigned short*)(ws + 128 * MiB);
    wmpT = (unsigned short*)(ws + 160 * MiB);
    hb = (unsigned short*)(ws + 192 * MiB);
  } else if (ws_size >= 160 * MiB) {
    nch = 2;
    gch = (unsigned short*)(ws + 0);
    xb = (unsigned short*)(ws + 0);
    wkvT = (unsigned short*)(ws + 32 * MiB);
    hb = (unsigned short*)(ws + 64 * MiB);
    wfcT = (unsigned short*)(ws + 96 * MiB);
    wmpT = (unsigned short*)(ws + 128 * MiB);
  } else {
    nch = 4;
    gch = (unsigned short*)(ws + 0);
    xb = (unsigned short*)(ws + 0);
    wkvT = (unsigned short*)(ws + 32 * MiB);
    hb = (unsigned short*)(ws + 32 * MiB);
    wfcT = (unsigned short*)(ws + 64 * MiB);
    wmpT = (unsigned short*)(ws + 96 * MiB);
  }

  cvt_bf16_kernel<<<(M * E / 8 + 255) / 256, 256, 0, stream>>>(x, xb, M * E / 8);
  transpose_cvt<<<dim3(E / 64, E / 64), 256, 0, stream>>>(w_kv, wkvT, E, E);
  transpose_cvt<<<dim3(F / 64, E / 64), 256, 0, stream>>>(w_fc, wfcT, E, F);
  transpose_cvt<<<dim3(E / 64, F / 64), 256, 0, stream>>>(w_mproj, wmpT, F, E);

  // t1 = x @ w_kv + b_kv + x
  gemm256<0><<<(M / 256) * (E / 256), 512, 0, stream>>>(xb, wkvT, b_kv, x,
                                                        tbuf, E, E);
  // h = LN1(t1) -> bf16
  ln_row<1><<<M, 256, 0, stream>>>(tbuf, ln1_g, ln1_b, hb);
  // g = gelu(h @ w_fc + b_fc); t2 = x + g @ w_mproj + b_mproj  (M-chunked)
  const int Mc = M / nch;
  for (int c = 0; c < nch; ++c) {
    const size_t roff = (size_t)c * Mc;
    gemm256<1><<<(Mc / 256) * (F / 256), 512, 0, stream>>>(
        hb + roff * E, wfcT, b_fc, nullptr, gch, F, E);
    gemm256<0><<<(Mc / 256) * (E / 256), 512, 0, stream>>>(
        gch, wmpT, b_mproj, x + roff * E, tbuf + roff * E, E, F);
  }
  // out = LN2(t2) in place
  ln_row<0><<<M, 256, 0, stream>>>(tbuf, ln2_g, ln2_b, out);
}